// Round 1
// baseline (2986.739 us; speedup 1.0000x reference)
//
#include <hip/hip_runtime.h>

#define EMB   64
#define NCON  50000
#define NVAR  100000
#define NEDGE 1600000
#define EPSLN 1e-5f

__device__ __forceinline__ float wsum64(float x) {
#pragma unroll
    for (int off = 32; off > 0; off >>= 1)
        x += __shfl_xor(x, off, 64);
    return x;
}

// Y[n][i] = (b?b[i]:0) + sum_j X[n][j] * W[i*wstride + j]   (wave per node, lane = i)
__global__ __launch_bounds__(256) void lin_kernel(
        const float* __restrict__ X, const float* __restrict__ W, int wstride,
        const float* __restrict__ b, float* __restrict__ Y, int N) {
    __shared__ float xbuf[4][EMB];
    const int wv = threadIdx.x >> 6;
    const int lane = threadIdx.x & 63;
    float w[EMB];
#pragma unroll
    for (int j4 = 0; j4 < 16; ++j4) {
        float4 t = *(const float4*)(W + lane * wstride + j4 * 4);
        w[4*j4+0] = t.x; w[4*j4+1] = t.y; w[4*j4+2] = t.z; w[4*j4+3] = t.w;
    }
    const float bias = b ? b[lane] : 0.0f;
    const int nW = gridDim.x * 4;
    for (int n = blockIdx.x * 4 + wv; n < N; n += nW) {
        xbuf[wv][lane] = X[(size_t)n * EMB + lane];
        float acc = bias;
#pragma unroll
        for (int j4 = 0; j4 < 16; ++j4) {
            float4 xv = *(const float4*)&xbuf[wv][j4 * 4];
            acc += xv.x * w[4*j4+0];
            acc += xv.y * w[4*j4+1];
            acc += xv.z * w[4*j4+2];
            acc += xv.w * w[4*j4+3];
        }
        Y[(size_t)n * EMB + lane] = acc;
    }
}

// Per edge: h = RL[dst] + LL[src] + ef*We; h = relu(LN(h)*g1+b1); t = h@Wf^T + bf;
// atomicAdd into AGG[dst].   (wave per edge, lane = output element)
__global__ __launch_bounds__(256) void edge_kernel(
        const int* __restrict__ dst, const int* __restrict__ src,
        const float* __restrict__ ef,
        const float* __restrict__ RL, const float* __restrict__ LL,
        const float* __restrict__ Wecol, const float* __restrict__ g1,
        const float* __restrict__ b1,
        const float* __restrict__ Wf, const float* __restrict__ bfp,
        float* __restrict__ AGG) {
    __shared__ float hbuf[4][EMB];
    const int wv = threadIdx.x >> 6;
    const int lane = threadIdx.x & 63;
    float w[EMB];
#pragma unroll
    for (int j4 = 0; j4 < 16; ++j4) {
        float4 t = *(const float4*)(Wf + lane * EMB + j4 * 4);
        w[4*j4+0] = t.x; w[4*j4+1] = t.y; w[4*j4+2] = t.z; w[4*j4+3] = t.w;
    }
    const float we = Wecol[lane];
    const float g  = g1[lane];
    const float bb = b1[lane];
    const float bf_ = bfp[lane];
    const int nW = gridDim.x * 4;
    for (int e = blockIdx.x * 4 + wv; e < NEDGE; e += nW) {
        const int d = dst[e];
        const int s = src[e];
        const float f = ef[e];
        float h = RL[(size_t)d * EMB + lane] + LL[(size_t)s * EMB + lane] + f * we;
        const float s1 = wsum64(h);
        const float s2 = wsum64(h * h);
        const float m   = s1 * (1.0f / EMB);
        const float var = s2 * (1.0f / EMB) - m * m;
        float hn = (h - m) * rsqrtf(var + EPSLN) * g + bb;
        hn = fmaxf(hn, 0.0f);
        hbuf[wv][lane] = hn;
        float acc = bf_;
#pragma unroll
        for (int j4 = 0; j4 < 16; ++j4) {
            float4 xv = *(const float4*)&hbuf[wv][j4 * 4];
            acc += xv.x * w[4*j4+0];
            acc += xv.y * w[4*j4+1];
            acc += xv.z * w[4*j4+2];
            acc += xv.w * w[4*j4+3];
        }
        atomicAdd(&AGG[(size_t)d * EMB + lane], acc);
    }
}

// z1 = LN(AGG)*g2+b2 ; o = relu(RB + z1@Wo1a^T) ; right += bo2 + o@Wo2^T
// RB already holds bo1 + right@Wo1[:,64:128]^T.
__global__ __launch_bounds__(256) void out_kernel(
        const float* __restrict__ AGG, const float* __restrict__ RB,
        float* __restrict__ right,
        const float* __restrict__ g2, const float* __restrict__ b2,
        const float* __restrict__ Wo1, const float* __restrict__ Wo2,
        const float* __restrict__ bo2, int N) {
    __shared__ float zbuf[4][EMB];
    __shared__ float obuf[4][EMB];
    const int wv = threadIdx.x >> 6;
    const int lane = threadIdx.x & 63;
    float w1[EMB], w2[EMB];
#pragma unroll
    for (int j4 = 0; j4 < 16; ++j4) {
        float4 t1 = *(const float4*)(Wo1 + lane * (2 * EMB) + j4 * 4);
        w1[4*j4+0] = t1.x; w1[4*j4+1] = t1.y; w1[4*j4+2] = t1.z; w1[4*j4+3] = t1.w;
        float4 t2 = *(const float4*)(Wo2 + lane * EMB + j4 * 4);
        w2[4*j4+0] = t2.x; w2[4*j4+1] = t2.y; w2[4*j4+2] = t2.z; w2[4*j4+3] = t2.w;
    }
    const float g  = g2[lane];
    const float bb = b2[lane];
    const float bo = bo2[lane];
    const int nW = gridDim.x * 4;
    for (int n = blockIdx.x * 4 + wv; n < N; n += nW) {
        const float a = AGG[(size_t)n * EMB + lane];
        const float s1 = wsum64(a);
        const float s2 = wsum64(a * a);
        const float m   = s1 * (1.0f / EMB);
        const float var = s2 * (1.0f / EMB) - m * m;
        const float z = (a - m) * rsqrtf(var + EPSLN) * g + bb;
        zbuf[wv][lane] = z;
        float acc = RB[(size_t)n * EMB + lane];
#pragma unroll
        for (int j4 = 0; j4 < 16; ++j4) {
            float4 zv = *(const float4*)&zbuf[wv][j4 * 4];
            acc += zv.x * w1[4*j4+0];
            acc += zv.y * w1[4*j4+1];
            acc += zv.z * w1[4*j4+2];
            acc += zv.w * w1[4*j4+3];
        }
        const float o = fmaxf(acc, 0.0f);
        obuf[wv][lane] = o;
        float acc2 = bo;
#pragma unroll
        for (int j4 = 0; j4 < 16; ++j4) {
            float4 ov = *(const float4*)&obuf[wv][j4 * 4];
            acc2 += ov.x * w2[4*j4+0];
            acc2 += ov.y * w2[4*j4+1];
            acc2 += ov.z * w2[4*j4+2];
            acc2 += ov.w * w2[4*j4+3];
        }
        right[(size_t)n * EMB + lane] += acc2;
    }
}

extern "C" void kernel_launch(void* const* d_in, const int* in_sizes, int n_in,
                              void* d_out, int out_size, void* d_ws, size_t ws_size,
                              hipStream_t stream) {
    const float* cf  = (const float*)d_in[0];
    const float* vfp = (const float*)d_in[1];
    const int*   ei  = (const int*)d_in[2];
    const float* ef  = (const float*)d_in[3];
    const float* Wl  = (const float*)d_in[4];
    const float* bl  = (const float*)d_in[5];
    const float* We  = (const float*)d_in[6];
    const float* Wr  = (const float*)d_in[7];
    const float* g1  = (const float*)d_in[8];
    const float* b1  = (const float*)d_in[9];
    const float* Wf  = (const float*)d_in[10];
    const float* bfp = (const float*)d_in[11];
    const float* g2  = (const float*)d_in[12];
    const float* b2  = (const float*)d_in[13];
    const float* Wo1 = (const float*)d_in[14];
    const float* bo1 = (const float*)d_in[15];
    const float* Wo2 = (const float*)d_in[16];
    const float* bo2 = (const float*)d_in[17];

    float* c = (float*)d_out;
    float* v = c + (size_t)NCON * EMB;
    hipMemcpyAsync(c, cf,  (size_t)NCON * EMB * sizeof(float), hipMemcpyDeviceToDevice, stream);
    hipMemcpyAsync(v, vfp, (size_t)NVAR * EMB * sizeof(float), hipMemcpyDeviceToDevice, stream);

    float* wsf = (float*)d_ws;
    float* RL  = wsf;                          // 100000*64 floats (also reused as RB)
    float* LL  = wsf + (size_t)NVAR * EMB;     // 100000*64
    float* AGG = wsf + (size_t)2 * NVAR * EMB; // 100000*64

    const int* ci = ei;
    const int* vi = ei + NEDGE;

    const dim3 blk(256);
    const int NB = 2048;

    for (int k = 0; k < 4; ++k) {
        const bool v2c = ((k & 1) == 0);
        float* right   = v2c ? c : v;
        float* left    = v2c ? v : c;
        const int Nr   = v2c ? NCON : NVAR;
        const int Nl   = v2c ? NVAR : NCON;
        const int* dst = v2c ? ci : vi;
        const int* src = v2c ? vi : ci;

        // RL = right @ Wl^T + bl ; LL = left @ Wr^T
        lin_kernel<<<NB, blk, 0, stream>>>(right, Wl + (size_t)k * EMB * EMB, EMB,
                                           bl + (size_t)k * EMB, RL, Nr);
        lin_kernel<<<NB, blk, 0, stream>>>(left,  Wr + (size_t)k * EMB * EMB, EMB,
                                           nullptr, LL, Nl);
        hipMemsetAsync(AGG, 0, (size_t)Nr * EMB * sizeof(float), stream);
        edge_kernel<<<NB, blk, 0, stream>>>(dst, src, ef, RL, LL,
                                            We + (size_t)k * EMB,
                                            g1 + (size_t)k * EMB, b1 + (size_t)k * EMB,
                                            Wf + (size_t)k * EMB * EMB,
                                            bfp + (size_t)k * EMB, AGG);
        // RB = right @ Wo1[:,64:128]^T + bo1   (into RL buffer, free after edge stage)
        lin_kernel<<<NB, blk, 0, stream>>>(right, Wo1 + (size_t)k * EMB * 2 * EMB + EMB,
                                           2 * EMB, bo1 + (size_t)k * EMB, RL, Nr);
        out_kernel<<<NB, blk, 0, stream>>>(AGG, RL, right,
                                           g2 + (size_t)k * EMB, b2 + (size_t)k * EMB,
                                           Wo1 + (size_t)k * EMB * 2 * EMB,
                                           Wo2 + (size_t)k * EMB * EMB,
                                           bo2 + (size_t)k * EMB, Nr);
    }
}